// Round 2
// baseline (257.087 us; speedup 1.0000x reference)
//
#include <hip/hip_runtime.h>
#include <hip/hip_bf16.h>
#include <math.h>

#define B_ 16
#define D_ 512
#define N_ 4096   // H*W
#define K_ 64

typedef __attribute__((ext_vector_type(8))) short bfrag;   // 8 bf16 = 4 VGPRs
typedef __attribute__((ext_vector_type(4))) float f32x4;

static __device__ __forceinline__ float bf2f(unsigned short u) {
    return __uint_as_float(((unsigned)u) << 16);
}
static __device__ __forceinline__ unsigned short f2bf(float v) {
    __hip_bfloat16 h = __float2bfloat16(v);   // RNE
    union { __hip_bfloat16 h; unsigned short u; } cv; cv.h = h; return cv.u;
}
static __device__ __forceinline__ void split3(float v, unsigned short& h,
                                              unsigned short& m, unsigned short& l) {
    h = f2bf(v); float r1 = v - bf2f(h);
    m = f2bf(r1); float r2 = r1 - bf2f(m);
    l = f2bf(r2);
}
static __device__ __forceinline__ void split2(float v, unsigned short& h,
                                              unsigned short& l) {
    h = f2bf(v); l = f2bf(v - bf2f(h));
}
#define MFMA(a, b, c) __builtin_amdgcn_mfma_f32_16x16x32_bf16((a), (b), (c), 0, 0, 0)

// XF (f32 x-tile [512 d][64 n]): row pitch 68 floats; 16B chunks rotated by row
// so phase-C b128 reads (16 c-lanes, consecutive d-rows) are 2-way max and
// staging writes (64 lanes along n at fixed d) stay a per-row permutation.
static __device__ __forceinline__ int xf_idx(int row, int col) {
    const int CH  = col >> 2;
    const int CHs = ((CH - 2 * (row & 7)) & 7) | (CH & 8);
    return row * 68 + CHs * 4 + (col & 3);
}
// ws (w limbs [64 k][64 n]): row pitch 72 shorts; 8-short chunks rotated by k
// -> phase-C bfrag reads land on bank group (ns*4 + q - c) % 8: 2-way max.
static __device__ __forceinline__ int ws_idx(int k, int n) {
    const int CH  = n >> 3;
    const int CHs = (CH - 2 * (k & 7)) & 7;
    return k * 72 + CHs * 8 + (n & 7);
}

// ---------------------------------------------------------------------------
// K0: pre-split conv_w into 3 bf16 limb planes [lv][64][512] (192 KB total).
// ---------------------------------------------------------------------------
__global__ __launch_bounds__(256) void k_prep(
    const float* __restrict__ conv_w, unsigned short* __restrict__ cwL)
{
    const int i = blockIdx.x * 256 + threadIdx.x;
    const float4 v = *(const float4*)&conv_w[i * 4];
    const float vv[4] = {v.x, v.y, v.z, v.w};
    unsigned short h[4], m[4], l[4];
    #pragma unroll
    for (int j = 0; j < 4; ++j) split3(vv[j], h[j], m[j], l[j]);
    *(ushort4*)&cwL[0 * (K_ * D_) + i * 4] = make_ushort4(h[0], h[1], h[2], h[3]);
    *(ushort4*)&cwL[1 * (K_ * D_) + i * 4] = make_ushort4(m[0], m[1], m[2], m[3]);
    *(ushort4*)&cwL[2 * (K_ * D_) + i * 4] = make_ushort4(l[0], l[1], l[2], l[3]);
}

// ---------------------------------------------------------------------------
// F1: fused logits + softmax + wsum + w.x^T.
// Grid 256 = B x 16 n-groups (1 block/CU), 512 threads = 8 waves (4 kw x 2 nw).
// Per 64-n sub-tile: phase A stages x once (f32 XF copy + split3 limbs) and
// runs the 3-limb logits MFMA; phase B does cross-wave softmax and writes
// 2-limb w to LDS; phase C (barrier-free) re-reads x from LDS and accumulates
// 16k x 256d per wave in registers across all 4 sub-tiles; one coalesced
// store to a per-n-group partial buffer (no atomics).
// LDS: XF 139264 + max(xs 15360 | ws 18432) + redm/reds 2048 = 159744 B.
// ---------------------------------------------------------------------------
__global__ __launch_bounds__(512, 2) void k_fused(
    const float* __restrict__ x, const unsigned short* __restrict__ cwL,
    const float* __restrict__ conv_b, float* __restrict__ vlad_part,
    float* __restrict__ wsumbuf)
{
    const int b    = blockIdx.x >> 4;
    const int g    = blockIdx.x & 15;          // n-group: n in [g*256, g*256+256)
    const int tid  = threadIdx.x;
    const int w    = tid >> 6;
    const int lane = tid & 63;
    const int q    = lane >> 4;
    const int c    = lane & 15;
    const int kw   = w >> 1;                   // k-quarter (16 k per wave)
    const int nw   = w & 1;                    // n-half (phase A) / d-half (phase C)
    const int dsub = w * 4;                    // staging d-rows per wave

    extern __shared__ char smem[];
    float*          xf   = (float*)smem;                          // [512][68] swz
    unsigned short* xsb  = (unsigned short*)(smem + 139264);      // [3][64][40]
    unsigned short* wsb_ = (unsigned short*)(smem + 139264);      // [2][64][72] (alias)
    float*          redm = (float*)(smem + 157696);               // [4][64]
    float*          reds = (float*)(smem + 158720);               // [4][64]

    f32x4 acc2[16];                            // wx accumulator: 16k x 256d / wave
    #pragma unroll
    for (int i = 0; i < 16; ++i) acc2[i] = (f32x4){0.f, 0.f, 0.f, 0.f};
    float wacc[4] = {0.f, 0.f, 0.f, 0.f};
    float bias[4];
    #pragma unroll
    for (int r = 0; r < 4; ++r) bias[r] = conv_b[kw * 16 + q * 4 + r];

    const unsigned short* cwp = cwL + (kw * 16 + c) * D_ + q * 8;

    #pragma unroll 1
    for (int t = 0; t < 4; ++t) {
        const int gn0 = g * 256 + t * 64;
        const float* xb = x + (size_t)b * ((size_t)D_ * N_) + gn0 + lane;

        f32x4 accA[2];
        accA[0] = (f32x4){0.f, 0.f, 0.f, 0.f};
        accA[1] = (f32x4){0.f, 0.f, 0.f, 0.f};

        // ---- phase A: stage x + 3-limb logits MFMA (prefetched d-loop)
        float gx[4];
        #pragma unroll
        for (int r = 0; r < 4; ++r) gx[r] = xb[(size_t)(dsub + r) * N_];

        #pragma unroll 1
        for (int d0 = 0; d0 < D_; d0 += 32) {
            // cw frags for this d0 (L2-hot, issued before the prefetch so the
            // MFMA wait doesn't drain nx)
            const bfrag af0 = *(const bfrag*)(cwp + d0);
            const bfrag af1 = *(const bfrag*)(cwp + K_ * D_ + d0);
            const bfrag af2 = *(const bfrag*)(cwp + 2 * K_ * D_ + d0);
            const int dn = (d0 + 32) & (D_ - 1);   // wraps (values unused last iter)
            float nx[4];
            #pragma unroll
            for (int r = 0; r < 4; ++r) nx[r] = xb[(size_t)(dn + dsub + r) * N_];

            #pragma unroll
            for (int r = 0; r < 4; ++r) xf[xf_idx(d0 + dsub + r, lane)] = gx[r];
            unsigned short h[4], m[4], l[4];
            #pragma unroll
            for (int r = 0; r < 4; ++r) split3(gx[r], h[r], m[r], l[r]);
            {
                const int Cs  = (dsub >> 3) ^ ((lane >> 3) & 3);
                const int dsw = Cs * 8 + (dsub & 7);
                *(ushort4*)&xsb[0 * 2560 + lane * 40 + dsw] = make_ushort4(h[0], h[1], h[2], h[3]);
                *(ushort4*)&xsb[1 * 2560 + lane * 40 + dsw] = make_ushort4(m[0], m[1], m[2], m[3]);
                *(ushort4*)&xsb[2 * 2560 + lane * 40 + dsw] = make_ushort4(l[0], l[1], l[2], l[3]);
            }
            __syncthreads();
            #pragma unroll
            for (int nt = 0; nt < 2; ++nt) {
                const int row = nw * 32 + nt * 16 + c;
                const int qs  = (q ^ ((row >> 3) & 3)) * 8;
                const bfrag bf0 = *(const bfrag*)&xsb[0 * 2560 + row * 40 + qs];
                const bfrag bf1 = *(const bfrag*)&xsb[1 * 2560 + row * 40 + qs];
                const bfrag bf2 = *(const bfrag*)&xsb[2 * 2560 + row * 40 + qs];
                f32x4 a = accA[nt];
                a = MFMA(af0, bf0, a);   // hh
                a = MFMA(af0, bf1, a);   // hm
                a = MFMA(af1, bf0, a);   // mh
                a = MFMA(af1, bf1, a);   // mm
                a = MFMA(af0, bf2, a);   // hl
                a = MFMA(af2, bf0, a);   // lh
                accA[nt] = a;
            }
            __syncthreads();
            #pragma unroll
            for (int r = 0; r < 4; ++r) gx[r] = nx[r];
        }

        // ---- phase B: bias + softmax over k (4 kw waves) + w limbs to LDS
        #pragma unroll
        for (int nt = 0; nt < 2; ++nt)
            #pragma unroll
            for (int r = 0; r < 4; ++r) accA[nt][r] += bias[r];

        {
            float ml[2];
            #pragma unroll
            for (int nt = 0; nt < 2; ++nt) {
                float mm = fmaxf(fmaxf(accA[nt][0], accA[nt][1]),
                                 fmaxf(accA[nt][2], accA[nt][3]));
                mm = fmaxf(mm, __shfl_xor(mm, 16));
                mm = fmaxf(mm, __shfl_xor(mm, 32));
                ml[nt] = mm;
            }
            if (q == 0) {
                redm[kw * 64 + nw * 32 + c]      = ml[0];
                redm[kw * 64 + nw * 32 + 16 + c] = ml[1];
            }
        }
        __syncthreads();
        float mall[2];
        #pragma unroll
        for (int nt = 0; nt < 2; ++nt) {
            const int n = nw * 32 + nt * 16 + c;
            mall[nt] = fmaxf(fmaxf(redm[n], redm[64 + n]),
                             fmaxf(redm[128 + n], redm[192 + n]));
        }
        float sl[2] = {0.f, 0.f};
        #pragma unroll
        for (int nt = 0; nt < 2; ++nt) {
            #pragma unroll
            for (int r = 0; r < 4; ++r) {
                const float e = __expf(accA[nt][r] - mall[nt]);
                accA[nt][r] = e;
                sl[nt] += e;
            }
            sl[nt] += __shfl_xor(sl[nt], 16);
            sl[nt] += __shfl_xor(sl[nt], 32);
        }
        if (q == 0) {
            reds[kw * 64 + nw * 32 + c]      = sl[0];
            reds[kw * 64 + nw * 32 + 16 + c] = sl[1];
        }
        __syncthreads();
        #pragma unroll
        for (int nt = 0; nt < 2; ++nt) {
            const int n = nw * 32 + nt * 16 + c;
            const float inv = 1.0f / (reds[n] + reds[64 + n] + reds[128 + n] + reds[192 + n]);
            #pragma unroll
            for (int r = 0; r < 4; ++r) {
                const float v = accA[nt][r] * inv;
                unsigned short hi, lo;
                split2(v, hi, lo);
                const int k = kw * 16 + q * 4 + r;
                wsb_[ws_idx(k, n)]        = hi;     // xs is dead; alias is safe
                wsb_[4608 + ws_idx(k, n)] = lo;
                wacc[r] += v;
            }
        }
        __syncthreads();   // ws visible to all waves

        // ---- phase C: wx += w . x^T from LDS, no barriers, 2-limb
        bfrag awh[2], awl[2];
        #pragma unroll
        for (int ns = 0; ns < 2; ++ns) {
            awh[ns] = *(const bfrag*)&wsb_[ws_idx(kw * 16 + c, ns * 32 + q * 8)];
            awl[ns] = *(const bfrag*)&wsb_[4608 + ws_idx(kw * 16 + c, ns * 32 + q * 8)];
        }
        #pragma unroll
        for (int i = 0; i < 16; ++i) {
            const int row = i * 32 + nw * 16 + c;   // d-row
            f32x4 a = acc2[i];
            #pragma unroll
            for (int ns = 0; ns < 2; ++ns) {
                const float4 v0 = *(const float4*)&xf[xf_idx(row, ns * 32 + q * 8)];
                const float4 v1 = *(const float4*)&xf[xf_idx(row, ns * 32 + q * 8 + 4)];
                const float vv[8] = {v0.x, v0.y, v0.z, v0.w, v1.x, v1.y, v1.z, v1.w};
                bfrag bh, bl;
                #pragma unroll
                for (int j = 0; j < 8; ++j) {
                    unsigned short hh, ll;
                    split2(vv[j], hh, ll);
                    bh[j] = (short)hh;
                    bl[j] = (short)ll;
                }
                a = MFMA(awh[ns], bh, a);
                a = MFMA(awh[ns], bl, a);
                a = MFMA(awl[ns], bh, a);
            }
            acc2[i] = a;
        }
        __syncthreads();   // protect XF/ws before next sub-tile overwrites
    }

    // ---- wsum: reduce over c-lanes, one atomic per (k, wave)
    #pragma unroll
    for (int msk = 1; msk < 16; msk <<= 1)
        #pragma unroll
        for (int r = 0; r < 4; ++r) wacc[r] += __shfl_xor(wacc[r], msk);
    if (c == 0)
        #pragma unroll
        for (int r = 0; r < 4; ++r)
            atomicAdd(&wsumbuf[b * K_ + kw * 16 + q * 4 + r], wacc[r]);

    // ---- partial store (coalesced along d, no atomics)
    float* vp = vlad_part + ((size_t)(b * 16 + g) * K_) * D_;
    #pragma unroll
    for (int i = 0; i < 16; ++i)
        #pragma unroll
        for (int r = 0; r < 4; ++r)
            vp[(size_t)(kw * 16 + q * 4 + r) * D_ + i * 32 + nw * 16 + c] = acc2[i][r];
}

// ---------------------------------------------------------------------------
// K3: reduce 16 n-group partials; v = vlad - wsum*c; row L2; global /8.
// ---------------------------------------------------------------------------
__global__ __launch_bounds__(256) void k_norm(
    const float* __restrict__ wsumbuf, const float* __restrict__ vlad_part,
    const float* __restrict__ centers, float* __restrict__ out)
{
    const int b   = blockIdx.x >> 6;
    const int k   = blockIdx.x & 63;
    const int tid = threadIdx.x;

    const float wsum = wsumbuf[b * K_ + k];

    const float* vp = vlad_part + ((size_t)(b * 16) * K_ + k) * D_;
    float a0 = 0.f, a1 = 0.f;
    #pragma unroll 4
    for (int gg = 0; gg < 16; ++gg) {
        a0 += vp[(size_t)gg * K_ * D_ + tid];
        a1 += vp[(size_t)gg * K_ * D_ + tid + 256];
    }
    const float* cr = centers + k * D_;
    const float v0 = a0 - wsum * cr[tid];
    const float v1 = a1 - wsum * cr[tid + 256];

    float ss = v0 * v0 + v1 * v1;
    __shared__ float red2[4];
    #pragma unroll
    for (int off = 32; off > 0; off >>= 1) ss += __shfl_down(ss, off, 64);
    if ((tid & 63) == 0) red2[tid >> 6] = ss;
    __syncthreads();
    const float nrm = sqrtf(red2[0] + red2[1] + red2[2] + red2[3]);
    const float scale = 1.0f / (8.0f * fmaxf(nrm, 1e-12f));

    float* outr = out + ((size_t)b * K_ + k) * D_;
    outr[tid]       = v0 * scale;
    outr[tid + 256] = v1 * scale;
}

extern "C" void kernel_launch(void* const* d_in, const int* in_sizes, int n_in,
                              void* d_out, int out_size, void* d_ws, size_t ws_size,
                              hipStream_t stream) {
    const float* x       = (const float*)d_in[0];
    const float* conv_w  = (const float*)d_in[1];
    const float* conv_b  = (const float*)d_in[2];
    const float* centers = (const float*)d_in[3];
    float* out = (float*)d_out;

    char* wsp = (char*)d_ws;
    float* vlad_part    = (float*)wsp;                               // 32 MiB
    float* wsumbuf      = (float*)(wsp + (32u << 20));               // 4 KiB
    unsigned short* cwL = (unsigned short*)(wsp + (32u << 20) + (1u << 16)); // 192 KiB

    hipMemsetAsync(wsumbuf, 0, B_ * K_ * sizeof(float), stream);

    static bool attr_set = false;
    if (!attr_set) {   // allow 156 KB dynamic LDS (gfx950 WG max = 160 KiB)
        (void)hipFuncSetAttribute((const void*)k_fused,
                                  hipFuncAttributeMaxDynamicSharedMemorySize, 159744);
        attr_set = true;
    }

    k_prep<<<32, 256, 0, stream>>>(conv_w, cwL);
    k_fused<<<B_ * 16, 512, 159744, stream>>>(x, cwL, conv_b, vlad_part, wsumbuf);
    k_norm<<<B_ * K_, 256, 0, stream>>>(wsumbuf, vlad_part, centers, out);
}